// Round 1
// baseline (724.943 us; speedup 1.0000x reference)
//
#include <hip/hip_runtime.h>

#define NN 50000
#define CC 128
#define EE 800000

typedef short bf16x8 __attribute__((ext_vector_type(8)));
typedef float f32x4 __attribute__((ext_vector_type(4)));

__device__ __forceinline__ float bf2f(unsigned int u16) {
  union { unsigned int u; float f; } x; x.u = u16 << 16; return x.f;
}
__device__ __forceinline__ unsigned short f2bf(float f) {
  union { float f; unsigned int u; } x; x.f = f;
  unsigned int u = x.u;
  unsigned int r = (u + 0x7fffu + ((u >> 16) & 1u)) >> 16;
  return (unsigned short)r;
}

// ---------------- casts ----------------
__global__ void cast_f2b_k(const float* __restrict__ in, unsigned short* __restrict__ out, int n4) {
  int i = blockIdx.x * blockDim.x + threadIdx.x;
  int stride = gridDim.x * blockDim.x;
  for (; i < n4; i += stride) {
    float4 v = ((const float4*)in)[i];
    ushort4 o;
    o.x = f2bf(v.x); o.y = f2bf(v.y); o.z = f2bf(v.z); o.w = f2bf(v.w);
    ((ushort4*)out)[i] = o;
  }
}

__global__ void zero_k(int* __restrict__ p, int n) {
  int i = blockIdx.x * blockDim.x + threadIdx.x;
  if (i < n) p[i] = 0;
}

// ---------------- CSR build ----------------
__global__ void hist_k(const int* __restrict__ dst, int* __restrict__ cnt, int n) {
  int i = blockIdx.x * blockDim.x + threadIdx.x;
  if (i < n) atomicAdd(&cnt[dst[i]], 1);
}

__global__ __launch_bounds__(1024) void scan_k(int* __restrict__ cnt /* in: counts, out: cursor */,
                                               int* __restrict__ rowptr, int N) {
  __shared__ int wexcl[16];
  __shared__ int s_carry, s_total;
  int tid = threadIdx.x, lane = tid & 63, w = tid >> 6;
  if (tid == 0) s_carry = 0;
  __syncthreads();
  for (int base = 0; base < N; base += 1024) {
    int i = base + tid;
    int v = (i < N) ? cnt[i] : 0;
    int x = v;
    #pragma unroll
    for (int off = 1; off < 64; off <<= 1) {
      int t = __shfl_up(x, off, 64);
      if (lane >= off) x += t;
    }
    if (lane == 63) wexcl[w] = x;
    __syncthreads();
    if (tid == 0) {
      int run = 0;
      #pragma unroll
      for (int j = 0; j < 16; ++j) { int t = wexcl[j]; wexcl[j] = run; run += t; }
      s_total = run;
    }
    __syncthreads();
    int excl = x - v + wexcl[w] + s_carry;
    if (i < N) { rowptr[i] = excl; cnt[i] = excl; }
    __syncthreads();
    if (tid == 0) s_carry += s_total;
    __syncthreads();
  }
  if (threadIdx.x == 0) rowptr[N] = s_carry;
}

__global__ void fill_k(const int* __restrict__ src, const int* __restrict__ dst,
                       int* __restrict__ cursor, int* __restrict__ colx, int n) {
  int i = blockIdx.x * blockDim.x + threadIdx.x;
  if (i < n) {
    int pos = atomicAdd(&cursor[dst[i]], 1);
    colx[pos] = src[i];
  }
}

// ---------------- m = state @ W_lin^T  (bf16 in, bf16 out) ----------------
__global__ __launch_bounds__(256) void lin_k(const unsigned short* __restrict__ Sb,
                                             const unsigned short* __restrict__ Wb,
                                             unsigned short* __restrict__ M, int N) {
  __shared__ unsigned short sA[32 * CC];
  const int tid = threadIdx.x;
  const int rowbase = blockIdx.x * 32;
  // stage 32x128 bf16 tile, XOR-swizzled 16B chunks (16 chunks/row)
  for (int i = tid; i < 512; i += 256) {
    int row = i >> 4, ch = i & 15;
    int grow = rowbase + row;
    uint4 v = make_uint4(0, 0, 0, 0);
    if (grow < N) v = *(const uint4*)(Sb + grow * CC + ch * 8);
    *(uint4*)(&sA[row * CC + ((ch ^ (row & 15)) * 8)]) = v;
  }
  __syncthreads();
  const int lane = tid & 63, w = tid >> 6;
  const int l15 = lane & 15, l4 = lane >> 4;
  f32x4 acc[2][2] = {};  // [ct2][rt]
  #pragma unroll
  for (int ks = 0; ks < 4; ++ks) {
    bf16x8 a[2];
    #pragma unroll
    for (int rt = 0; rt < 2; ++rt) {
      int row = rt * 16 + l15;
      a[rt] = *(const bf16x8*)(&sA[row * CC + (((ks * 4 + l4) ^ l15) * 8)]);
    }
    #pragma unroll
    for (int ct2 = 0; ct2 < 2; ++ct2) {
      int colg = (w + 4 * ct2) * 16 + l15;
      bf16x8 b = *(const bf16x8*)(Wb + colg * CC + ks * 32 + 8 * l4);
      #pragma unroll
      for (int rt = 0; rt < 2; ++rt)
        acc[ct2][rt] = __builtin_amdgcn_mfma_f32_16x16x32_bf16(a[rt], b, acc[ct2][rt], 0, 0, 0);
    }
  }
  #pragma unroll
  for (int ct2 = 0; ct2 < 2; ++ct2) {
    int colg = (w + 4 * ct2) * 16 + l15;
    #pragma unroll
    for (int rt = 0; rt < 2; ++rt)
      #pragma unroll
      for (int i = 0; i < 4; ++i) {
        int row = rowbase + rt * 16 + 4 * l4 + i;
        if (row < N) M[row * CC + colg] = f2bf(acc[ct2][rt][i]);
      }
  }
}

// ---------------- propagated = segment_sum(m[src], dst) ----------------
__global__ __launch_bounds__(256) void agg_k(const unsigned short* __restrict__ M,
                                             const int* __restrict__ rowptr,
                                             const int* __restrict__ colx,
                                             unsigned short* __restrict__ P, int N) {
  int wid = (blockIdx.x * 256 + threadIdx.x) >> 6;
  int lane = threadIdx.x & 63;
  if (wid >= N) return;
  int beg = rowptr[wid], end = rowptr[wid + 1];
  float a0 = 0.f, a1 = 0.f;
  for (int e = beg; e < end; ++e) {
    int s = colx[e];
    unsigned int v = *(const unsigned int*)(M + s * CC + lane * 2);
    a0 += bf2f(v & 0xffffu);
    a1 += bf2f(v >> 16);
  }
  unsigned int o = (unsigned int)f2bf(a0) | ((unsigned int)f2bf(a1) << 16);
  *(unsigned int*)(P + wid * CC + lane * 2) = o;
}

// ---------------- fused gate GEMMs + GRU elementwise ----------------
__global__ __launch_bounds__(256) void gru_k(const unsigned short* __restrict__ Pb,
                                             unsigned short* Sb,         // in (stage) + out (bf16 state)
                                             const float* h_in, float* h_out,
                                             const unsigned short* __restrict__ Wih,
                                             const unsigned short* __restrict__ Whh,
                                             const float* __restrict__ bih,
                                             const float* __restrict__ bhh, int N) {
  __shared__ unsigned short sA[2][32 * CC];  // [0]=prop, [1]=state
  const int tid = threadIdx.x;
  const int rowbase = blockIdx.x * 32;
  for (int i = tid; i < 1024; i += 256) {
    int mat = i >> 9;
    int j = i & 511;
    int row = j >> 4, ch = j & 15;
    int grow = rowbase + row;
    const unsigned short* srcp = mat ? (const unsigned short*)Sb : Pb;
    uint4 v = make_uint4(0, 0, 0, 0);
    if (grow < N) v = *(const uint4*)(srcp + grow * CC + ch * 8);
    *(uint4*)(&sA[mat][row * CC + ((ch ^ (row & 15)) * 8)]) = v;
  }
  __syncthreads();
  const int lane = tid & 63, w = tid >> 6;
  const int l15 = lane & 15, l4 = lane >> 4;
  f32x4 acc[2][2][3][2] = {};  // [ct2][mat][p][rt]
  #pragma unroll
  for (int ks = 0; ks < 4; ++ks) {
    bf16x8 a[2][2];
    #pragma unroll
    for (int mat = 0; mat < 2; ++mat)
      #pragma unroll
      for (int rt = 0; rt < 2; ++rt) {
        int row = rt * 16 + l15;
        a[mat][rt] = *(const bf16x8*)(&sA[mat][row * CC + (((ks * 4 + l4) ^ l15) * 8)]);
      }
    #pragma unroll
    for (int ct2 = 0; ct2 < 2; ++ct2)
      #pragma unroll
      for (int mat = 0; mat < 2; ++mat) {
        const unsigned short* Wm = mat ? Whh : Wih;
        #pragma unroll
        for (int p = 0; p < 3; ++p) {
          int colg = (w + 4 * ct2) * 16 + 128 * p + l15;
          bf16x8 b = *(const bf16x8*)(Wm + colg * CC + ks * 32 + 8 * l4);
          #pragma unroll
          for (int rt = 0; rt < 2; ++rt)
            acc[ct2][mat][p][rt] =
                __builtin_amdgcn_mfma_f32_16x16x32_bf16(a[mat][rt], b, acc[ct2][mat][p][rt], 0, 0, 0);
        }
      }
  }
  #pragma unroll
  for (int ct2 = 0; ct2 < 2; ++ct2) {
    int c = (w + 4 * ct2) * 16 + l15;
    float bir = bih[c], biz = bih[c + 128], bin_ = bih[c + 256];
    float bhr = bhh[c], bhz = bhh[c + 128], bhn = bhh[c + 256];
    #pragma unroll
    for (int rt = 0; rt < 2; ++rt) {
      #pragma unroll
      for (int i = 0; i < 4; ++i) {
        int row = rowbase + rt * 16 + 4 * l4 + i;
        if (row < N) {
          float gir = acc[ct2][0][0][rt][i] + bir;
          float giz = acc[ct2][0][1][rt][i] + biz;
          float gin = acc[ct2][0][2][rt][i] + bin_;
          float ghr = acc[ct2][1][0][rt][i] + bhr;
          float ghz = acc[ct2][1][1][rt][i] + bhz;
          float ghn = acc[ct2][1][2][rt][i] + bhn;
          float r = 1.f / (1.f + __expf(-(gir + ghr)));
          float z = 1.f / (1.f + __expf(-(giz + ghz)));
          float n = tanhf(gin + r * ghn);
          float h = h_in[row * CC + c];
          float o = (1.f - z) * n + z * h;
          h_out[row * CC + c] = o;
          Sb[row * CC + c] = f2bf(o);
        }
      }
    }
  }
}

extern "C" void kernel_launch(void* const* d_in, const int* in_sizes, int n_in,
                              void* d_out, int out_size, void* d_ws, size_t ws_size,
                              hipStream_t stream) {
  const float* x    = (const float*)d_in[0];
  const int*   ei   = (const int*)d_in[1];
  const float* Wlin = (const float*)d_in[2];
  const float* Wih  = (const float*)d_in[3];
  const float* Whh  = (const float*)d_in[4];
  const float* bih  = (const float*)d_in[5];
  const float* bhh  = (const float*)d_in[6];
  float* out = (float*)d_out;

  char* ws = (char*)d_ws;
  size_t off = 0;
  auto alloc = [&](size_t bytes) -> void* {
    void* p = ws + off;
    off += (bytes + 255) & ~(size_t)255;
    return p;
  };
  unsigned short* Sb   = (unsigned short*)alloc((size_t)NN * CC * 2);
  unsigned short* Mb   = (unsigned short*)alloc((size_t)NN * CC * 2);
  unsigned short* Prb  = (unsigned short*)alloc((size_t)NN * CC * 2);
  float*          Sf   = (float*)alloc((size_t)NN * CC * 4);
  unsigned short* Wlb  = (unsigned short*)alloc((size_t)CC * CC * 2);
  unsigned short* Wihb = (unsigned short*)alloc((size_t)3 * CC * CC * 2);
  unsigned short* Whhb = (unsigned short*)alloc((size_t)3 * CC * CC * 2);
  int* rowptr = (int*)alloc((size_t)(NN + 1) * 4);
  int* cursor = (int*)alloc((size_t)NN * 4);
  int* colx   = (int*)alloc((size_t)EE * 4);

  const int* srcI = ei;
  const int* dstI = ei + EE;

  cast_f2b_k<<<1024, 256, 0, stream>>>(x, Sb, NN * CC / 4);
  cast_f2b_k<<<16, 256, 0, stream>>>(Wlin, Wlb, CC * CC / 4);
  cast_f2b_k<<<48, 256, 0, stream>>>(Wih, Wihb, 3 * CC * CC / 4);
  cast_f2b_k<<<48, 256, 0, stream>>>(Whh, Whhb, 3 * CC * CC / 4);

  zero_k<<<(NN + 255) / 256, 256, 0, stream>>>(cursor, NN);
  hist_k<<<(EE + 255) / 256, 256, 0, stream>>>(dstI, cursor, EE);
  scan_k<<<1, 1024, 0, stream>>>(cursor, rowptr, NN);
  fill_k<<<(EE + 255) / 256, 256, 0, stream>>>(srcI, dstI, cursor, colx, EE);

  const int gemmBlocks = (NN + 31) / 32;
  const int aggBlocks  = (NN + 3) / 4;

  // step 1 (h = x)
  lin_k<<<gemmBlocks, 256, 0, stream>>>(Sb, Wlb, Mb, NN);
  agg_k<<<aggBlocks, 256, 0, stream>>>(Mb, rowptr, colx, Prb, NN);
  gru_k<<<gemmBlocks, 256, 0, stream>>>(Prb, Sb, x, Sf, Wihb, Whhb, bih, bhh, NN);
  // step 2
  lin_k<<<gemmBlocks, 256, 0, stream>>>(Sb, Wlb, Mb, NN);
  agg_k<<<aggBlocks, 256, 0, stream>>>(Mb, rowptr, colx, Prb, NN);
  gru_k<<<gemmBlocks, 256, 0, stream>>>(Prb, Sb, Sf, Sf, Wihb, Whhb, bih, bhh, NN);
  // step 3 (write final state to d_out)
  lin_k<<<gemmBlocks, 256, 0, stream>>>(Sb, Wlb, Mb, NN);
  agg_k<<<aggBlocks, 256, 0, stream>>>(Mb, rowptr, colx, Prb, NN);
  gru_k<<<gemmBlocks, 256, 0, stream>>>(Prb, Sb, Sf, out, Wihb, Whhb, bih, bhh, NN);
}

// Round 2
// 654.459 us; speedup vs baseline: 1.1077x; 1.1077x over previous
//
#include <hip/hip_runtime.h>

#define NN 50000
#define CC 128
#define EE 800000
#define NT 1563          // ceil(NN/32)
#define NBLK 196         // ceil(NN/256)

typedef short bf16x8 __attribute__((ext_vector_type(8)));
typedef float f32x4 __attribute__((ext_vector_type(4)));

__device__ __forceinline__ float bf2f(unsigned int u16) {
  union { unsigned int u; float f; } x; x.u = u16 << 16; return x.f;
}
__device__ __forceinline__ unsigned short f2bf(float f) {
  union { float f; unsigned int u; } x; x.f = f;
  unsigned int u = x.u;
  unsigned int r = (u + 0x7fffu + ((u >> 16) & 1u)) >> 16;
  return (unsigned short)r;
}

// ---------------- casts ----------------
__global__ void cast_f2b_k(const float* __restrict__ in, unsigned short* __restrict__ out, int n4) {
  int i = blockIdx.x * blockDim.x + threadIdx.x;
  int stride = gridDim.x * blockDim.x;
  for (; i < n4; i += stride) {
    float4 v = ((const float4*)in)[i];
    ushort4 o;
    o.x = f2bf(v.x); o.y = f2bf(v.y); o.z = f2bf(v.z); o.w = f2bf(v.w);
    ((ushort4*)out)[i] = o;
  }
}

__global__ void castW_k(const float* __restrict__ Wlin, const float* __restrict__ Wih,
                        const float* __restrict__ Whh, unsigned short* __restrict__ Wlb,
                        unsigned short* __restrict__ Wihb, unsigned short* __restrict__ Whhb) {
  int i = blockIdx.x * 256 + threadIdx.x;  // float4 index; total 28672
  if (i >= 28672) return;
  const float* src; unsigned short* dst; int j;
  if (i < 4096)       { src = Wlin; dst = Wlb;  j = i; }
  else if (i < 16384) { src = Wih;  dst = Wihb; j = i - 4096; }
  else                { src = Whh;  dst = Whhb; j = i - 16384; }
  float4 v = ((const float4*)src)[j];
  ushort4 o;
  o.x = f2bf(v.x); o.y = f2bf(v.y); o.z = f2bf(v.z); o.w = f2bf(v.w);
  ((ushort4*)dst)[j] = o;
}

__global__ void zero_k(int* __restrict__ p, int n) {
  int i = blockIdx.x * blockDim.x + threadIdx.x;
  if (i < n) p[i] = 0;
}

// ---------------- CSR build ----------------
__global__ void hist_k(const int* __restrict__ dst, int* __restrict__ cnt, int n) {
  int i = blockIdx.x * blockDim.x + threadIdx.x;
  if (i < n) atomicAdd(&cnt[dst[i]], 1);
}

// block-local exclusive scan of cnt -> localexcl (into rowptr), block totals -> bsum
__global__ __launch_bounds__(256) void scan1_k(const int* __restrict__ cnt,
                                               int* __restrict__ rowptr,
                                               int* __restrict__ bsum, int N) {
  __shared__ int wtot[4];
  int tid = threadIdx.x, lane = tid & 63, w = tid >> 6;
  int i = blockIdx.x * 256 + tid;
  int v = (i < N) ? cnt[i] : 0;
  int x = v;
  #pragma unroll
  for (int off = 1; off < 64; off <<= 1) {
    int t = __shfl_up(x, off, 64);
    if (lane >= off) x += t;
  }
  if (lane == 63) wtot[w] = x;
  __syncthreads();
  int woff = 0;
  for (int j = 0; j < w; ++j) woff += wtot[j];
  int excl = x - v + woff;
  if (i < N) rowptr[i] = excl;
  if (tid == 255) bsum[blockIdx.x] = excl + v;
}

// exclusive scan of bsum (NB<=256) in place; total -> rowptr[NN]
__global__ __launch_bounds__(256) void scan2_k(int* __restrict__ bsum, int* __restrict__ rowptr, int NB) {
  __shared__ int wtot[4];
  int tid = threadIdx.x, lane = tid & 63, w = tid >> 6;
  int v = (tid < NB) ? bsum[tid] : 0;
  int x = v;
  #pragma unroll
  for (int off = 1; off < 64; off <<= 1) {
    int t = __shfl_up(x, off, 64);
    if (lane >= off) x += t;
  }
  if (lane == 63) wtot[w] = x;
  __syncthreads();
  int woff = 0;
  for (int j = 0; j < w; ++j) woff += wtot[j];
  int excl = x - v + woff;
  if (tid < NB) bsum[tid] = excl;
  if (tid == 255) rowptr[NN] = excl + v;
}

__global__ void scan3_k(int* __restrict__ rowptr, const int* __restrict__ bsum,
                        int* __restrict__ cursor, int N) {
  int i = blockIdx.x * 256 + threadIdx.x;
  if (i < N) {
    int r = rowptr[i] + bsum[i >> 8];
    rowptr[i] = r;
    cursor[i] = r;
  }
}

__global__ void fill_k(const int* __restrict__ src, const int* __restrict__ dst,
                       int* __restrict__ cursor, int* __restrict__ colx, int n) {
  int i = blockIdx.x * blockDim.x + threadIdx.x;
  if (i < n) {
    int pos = atomicAdd(&cursor[dst[i]], 1);
    colx[pos] = src[i];
  }
}

// ---------------- m = state @ W_lin^T : weights-stationary, LDS-resident ----------------
__global__ __launch_bounds__(256) void lin2_k(const unsigned short* __restrict__ Sb,
                                              const unsigned short* __restrict__ Wlb,
                                              unsigned short* __restrict__ M) {
  __shared__ unsigned short sW[128][128];     // 32 KB, [out-col][k], 16B-chunk XOR swizzle
  __shared__ unsigned short sA[2][32][128];   // 16 KB, double-buffered row tile
  const int tid = threadIdx.x;
  const int lane = tid & 63, w = tid >> 6;
  const int l15 = lane & 15, l4 = lane >> 4;

  for (int idx = tid; idx < 2048; idx += 256) {   // 128 cols x 16 chunks
    int c = idx >> 4, ch = idx & 15;
    uint4 v = *(const uint4*)(Wlb + c * 128 + ch * 8);
    *(uint4*)&sW[c][((ch ^ (c & 15)) * 8)] = v;
  }

  auto loadA = [&](int t, uint4* r) {
    int rowbase = t * 32;
    #pragma unroll
    for (int k = 0; k < 2; ++k) {
      int idx = k * 256 + tid;
      int row = idx >> 4, ch = idx & 15;
      int grow = rowbase + row;
      r[k] = (grow < NN) ? *(const uint4*)(Sb + grow * 128 + ch * 8) : make_uint4(0, 0, 0, 0);
    }
  };
  auto writeA = [&](int buf, const uint4* r) {
    #pragma unroll
    for (int k = 0; k < 2; ++k) {
      int idx = k * 256 + tid;
      int row = idx >> 4, ch = idx & 15;
      *(uint4*)&sA[buf][row][((ch ^ (row & 15)) * 8)] = r[k];
    }
  };

  uint4 pre[2];
  int t0 = blockIdx.x;
  if (t0 < NT) loadA(t0, pre);
  writeA(0, pre);
  int cur = 0;
  for (int t = t0; t < NT; t += gridDim.x) {
    __syncthreads();
    int tn = t + gridDim.x;
    uint4 nxt[2];
    if (tn < NT) loadA(tn, nxt);

    f32x4 acc[2][2] = {};  // [cc][rt]
    #pragma unroll
    for (int ks = 0; ks < 4; ++ks) {
      bf16x8 a[2];
      #pragma unroll
      for (int rt = 0; rt < 2; ++rt) {
        int row = rt * 16 + l15;
        a[rt] = *(const bf16x8*)&sA[cur][row][(((ks * 4 + l4) ^ l15) * 8)];
      }
      #pragma unroll
      for (int cc = 0; cc < 2; ++cc) {
        int c = (2 * w + cc) * 16 + l15;
        bf16x8 b = *(const bf16x8*)&sW[c][(((ks * 4 + l4) ^ l15) * 8)];
        acc[cc][0] = __builtin_amdgcn_mfma_f32_16x16x32_bf16(a[0], b, acc[cc][0], 0, 0, 0);
        acc[cc][1] = __builtin_amdgcn_mfma_f32_16x16x32_bf16(a[1], b, acc[cc][1], 0, 0, 0);
      }
    }
    int rowbase = t * 32;
    #pragma unroll
    for (int cc = 0; cc < 2; ++cc) {
      int c = (2 * w + cc) * 16 + l15;
      #pragma unroll
      for (int rt = 0; rt < 2; ++rt)
        #pragma unroll
        for (int i = 0; i < 4; ++i) {
          int row = rowbase + rt * 16 + l4 * 4 + i;
          if (row < NN) M[row * 128 + c] = f2bf(acc[cc][rt][i]);
        }
    }
    if (tn < NT) writeA(cur ^ 1, nxt);
    cur ^= 1;
  }
}

// ---------------- propagated = segment_sum(m[src], dst) ----------------
__global__ __launch_bounds__(256) void agg_k(const unsigned short* __restrict__ M,
                                             const int* __restrict__ rowptr,
                                             const int* __restrict__ colx,
                                             unsigned short* __restrict__ P, int N) {
  int wid = (blockIdx.x * 256 + threadIdx.x) >> 6;
  int lane = threadIdx.x & 63;
  if (wid >= N) return;
  int beg = rowptr[wid], end = rowptr[wid + 1];
  float a0 = 0.f, a1 = 0.f;
  for (int e = beg; e < end; ++e) {
    int s = colx[e];
    unsigned int v = *(const unsigned int*)(M + s * CC + lane * 2);
    a0 += bf2f(v & 0xffffu);
    a1 += bf2f(v >> 16);
  }
  unsigned int o = (unsigned int)f2bf(a0) | ((unsigned int)f2bf(a1) << 16);
  *(unsigned int*)(P + wid * CC + lane * 2) = o;
}

// ---------------- fused gate GEMMs + GRU elementwise (weights-stationary) ----------------
// grid = 512: blockIdx&1 = column half (64 gate-cols), blockIdx>>1 = row group (stride 256)
__global__ __launch_bounds__(256) void gru2_k(const unsigned short* __restrict__ Pb,
                                              const unsigned short* __restrict__ Sb_in,
                                              unsigned short* __restrict__ Sb_out,
                                              const float* __restrict__ h_in,
                                              float* __restrict__ h_out,
                                              const unsigned short* __restrict__ Wihb,
                                              const unsigned short* __restrict__ Whhb,
                                              const float* __restrict__ bih,
                                              const float* __restrict__ bhh) {
  __shared__ unsigned short sW[6][64][128];      // 96 KB: panels ihr,ihz,ihn,hhr,hhz,hhn
  __shared__ unsigned short sA[2][2][32][128];   // 32 KB: [buf][mat 0=prop 1=state]
  const int tid = threadIdx.x;
  const int half = blockIdx.x & 1;
  const int group = blockIdx.x >> 1;
  const int lane = tid & 63, w = tid >> 6;
  const int l15 = lane & 15, l4 = lane >> 4;

  // stage 6 x 64x128 bf16 weight panels (this column half), XOR-swizzled
  for (int idx = tid; idx < 6144; idx += 256) {
    int pi = idx >> 10, j = idx & 1023, c = j >> 4, ch = j & 15;
    const unsigned short* Wm = (pi < 3) ? Wihb : Whhb;
    int p = (pi < 3) ? pi : pi - 3;
    int gcol = p * 128 + half * 64 + c;
    uint4 v = *(const uint4*)(Wm + gcol * 128 + ch * 8);
    *(uint4*)&sW[pi][c][((ch ^ (c & 15)) * 8)] = v;
  }

  const int c_loc = w * 16 + l15;     // wave owns 16 cols of the 64-col half
  const int cg = half * 64 + c_loc;
  const float bir = bih[cg], biz = bih[cg + 128], bin_ = bih[cg + 256];
  const float bhr = bhh[cg], bhz = bhh[cg + 128], bhn = bhh[cg + 256];

  auto loadA = [&](int t, uint4* r) {
    int rowbase = t * 32;
    #pragma unroll
    for (int k = 0; k < 4; ++k) {
      int idx = k * 256 + tid;                // 1024 chunks: [mat][row][ch]
      int mat = idx >> 9, j = idx & 511, row = j >> 4, ch = j & 15;
      int grow = rowbase + row;
      const unsigned short* srcp = mat ? Sb_in : Pb;
      r[k] = (grow < NN) ? *(const uint4*)(srcp + grow * 128 + ch * 8) : make_uint4(0, 0, 0, 0);
    }
  };
  auto writeA = [&](int buf, const uint4* r) {
    #pragma unroll
    for (int k = 0; k < 4; ++k) {
      int idx = k * 256 + tid;
      int mat = idx >> 9, j = idx & 511, row = j >> 4, ch = j & 15;
      *(uint4*)&sA[buf][mat][row][((ch ^ (row & 15)) * 8)] = r[k];
    }
  };

  uint4 pre[4];
  int t0 = group;
  loadA(t0, pre);     // group < 256 <= NT always valid
  writeA(0, pre);
  int cur = 0;
  for (int t = t0; t < NT; t += 256) {
    __syncthreads();   // sA[cur] (and sW on first iter) ready
    int tn = t + 256;
    uint4 nxt[4];
    if (tn < NT) loadA(tn, nxt);

    f32x4 acc[6][2] = {};   // [panel][row-frag]
    #pragma unroll
    for (int ks = 0; ks < 4; ++ks) {
      bf16x8 a[2][2];
      #pragma unroll
      for (int mat = 0; mat < 2; ++mat)
        #pragma unroll
        for (int rt = 0; rt < 2; ++rt) {
          int row = rt * 16 + l15;
          a[mat][rt] = *(const bf16x8*)&sA[cur][mat][row][(((ks * 4 + l4) ^ l15) * 8)];
        }
      #pragma unroll
      for (int pi = 0; pi < 6; ++pi) {
        bf16x8 b = *(const bf16x8*)&sW[pi][c_loc][(((ks * 4 + l4) ^ l15) * 8)];
        int am = (pi < 3) ? 0 : 1;
        acc[pi][0] = __builtin_amdgcn_mfma_f32_16x16x32_bf16(a[am][0], b, acc[pi][0], 0, 0, 0);
        acc[pi][1] = __builtin_amdgcn_mfma_f32_16x16x32_bf16(a[am][1], b, acc[pi][1], 0, 0, 0);
      }
    }

    int rowbase = t * 32;
    #pragma unroll
    for (int rt = 0; rt < 2; ++rt)
      #pragma unroll
      for (int i = 0; i < 4; ++i) {
        int row = rowbase + rt * 16 + l4 * 4 + i;
        if (row < NN) {
          float gir = acc[0][rt][i] + bir;
          float giz = acc[1][rt][i] + biz;
          float gin = acc[2][rt][i] + bin_;
          float ghr = acc[3][rt][i] + bhr;
          float ghz = acc[4][rt][i] + bhz;
          float ghn = acc[5][rt][i] + bhn;
          float r = 1.f / (1.f + __expf(-(gir + ghr)));
          float z = 1.f / (1.f + __expf(-(giz + ghz)));
          float n = tanhf(gin + r * ghn);
          float h = h_in[row * 128 + cg];
          float o = (1.f - z) * n + z * h;
          h_out[row * 128 + cg] = o;
          Sb_out[row * 128 + cg] = f2bf(o);
        }
      }
    if (tn < NT) writeA(cur ^ 1, nxt);
    cur ^= 1;
  }
}

extern "C" void kernel_launch(void* const* d_in, const int* in_sizes, int n_in,
                              void* d_out, int out_size, void* d_ws, size_t ws_size,
                              hipStream_t stream) {
  const float* x    = (const float*)d_in[0];
  const int*   ei   = (const int*)d_in[1];
  const float* Wlin = (const float*)d_in[2];
  const float* Wih  = (const float*)d_in[3];
  const float* Whh  = (const float*)d_in[4];
  const float* bih  = (const float*)d_in[5];
  const float* bhh  = (const float*)d_in[6];
  float* out = (float*)d_out;

  char* ws = (char*)d_ws;
  size_t off = 0;
  auto alloc = [&](size_t bytes) -> void* {
    void* p = ws + off;
    off += (bytes + 255) & ~(size_t)255;
    return p;
  };
  unsigned short* SbA  = (unsigned short*)alloc((size_t)NN * CC * 2);
  unsigned short* SbB  = (unsigned short*)alloc((size_t)NN * CC * 2);
  unsigned short* Mb   = (unsigned short*)alloc((size_t)NN * CC * 2);
  unsigned short* Prb  = (unsigned short*)alloc((size_t)NN * CC * 2);
  float*          Sf   = (float*)alloc((size_t)NN * CC * 4);
  unsigned short* Wlb  = (unsigned short*)alloc((size_t)CC * CC * 2);
  unsigned short* Wihb = (unsigned short*)alloc((size_t)3 * CC * CC * 2);
  unsigned short* Whhb = (unsigned short*)alloc((size_t)3 * CC * CC * 2);
  int* rowptr = (int*)alloc((size_t)(NN + 1) * 4);
  int* cursor = (int*)alloc((size_t)NN * 4);
  int* colx   = (int*)alloc((size_t)EE * 4);
  int* bsum   = (int*)alloc(256 * 4);

  const int* srcI = ei;
  const int* dstI = ei + EE;

  cast_f2b_k<<<1024, 256, 0, stream>>>(x, SbA, NN * CC / 4);
  castW_k<<<112, 256, 0, stream>>>(Wlin, Wih, Whh, Wlb, Wihb, Whhb);

  zero_k<<<NBLK, 256, 0, stream>>>(cursor, NN);
  hist_k<<<(EE + 255) / 256, 256, 0, stream>>>(dstI, cursor, EE);
  scan1_k<<<NBLK, 256, 0, stream>>>(cursor, rowptr, bsum, NN);
  scan2_k<<<1, 256, 0, stream>>>(bsum, rowptr, NBLK);
  scan3_k<<<NBLK, 256, 0, stream>>>(rowptr, bsum, cursor, NN);
  fill_k<<<(EE + 255) / 256, 256, 0, stream>>>(srcI, dstI, cursor, colx, EE);

  const int aggBlocks = (NN + 3) / 4;

  // step 1 (h = x)
  lin2_k<<<782, 256, 0, stream>>>(SbA, Wlb, Mb);
  agg_k<<<aggBlocks, 256, 0, stream>>>(Mb, rowptr, colx, Prb, NN);
  gru2_k<<<512, 256, 0, stream>>>(Prb, SbA, SbB, x, Sf, Wihb, Whhb, bih, bhh);
  // step 2
  lin2_k<<<782, 256, 0, stream>>>(SbB, Wlb, Mb);
  agg_k<<<aggBlocks, 256, 0, stream>>>(Mb, rowptr, colx, Prb, NN);
  gru2_k<<<512, 256, 0, stream>>>(Prb, SbB, SbA, Sf, Sf, Wihb, Whhb, bih, bhh);
  // step 3 (final state -> d_out)
  lin2_k<<<782, 256, 0, stream>>>(SbA, Wlb, Mb);
  agg_k<<<aggBlocks, 256, 0, stream>>>(Mb, rowptr, colx, Prb, NN);
  gru2_k<<<512, 256, 0, stream>>>(Prb, SbA, SbB, Sf, out, Wihb, Whhb, bih, bhh);
}

// Round 4
// 511.733 us; speedup vs baseline: 1.4166x; 1.2789x over previous
//
#include <hip/hip_runtime.h>

#define NN 50000
#define CC 128
#define EE 800000
#define NT 1563          // ceil(NN/32)
#define NBLK 196         // ceil(NN/256)

typedef short bf16x8 __attribute__((ext_vector_type(8)));
typedef float f32x4 __attribute__((ext_vector_type(4)));

__device__ __forceinline__ float bf2f(unsigned int u16) {
  union { unsigned int u; float f; } x; x.u = u16 << 16; return x.f;
}
__device__ __forceinline__ unsigned short f2bf(float f) {
  union { float f; unsigned int u; } x; x.f = f;
  unsigned int u = x.u;
  unsigned int r = (u + 0x7fffu + ((u >> 16) & 1u)) >> 16;
  return (unsigned short)r;
}

// ---------------- casts ----------------
__global__ void cast_f2b_k(const float* __restrict__ in, unsigned short* __restrict__ out, int n4) {
  int i = blockIdx.x * blockDim.x + threadIdx.x;
  int stride = gridDim.x * blockDim.x;
  for (; i < n4; i += stride) {
    float4 v = ((const float4*)in)[i];
    ushort4 o;
    o.x = f2bf(v.x); o.y = f2bf(v.y); o.z = f2bf(v.z); o.w = f2bf(v.w);
    ((ushort4*)out)[i] = o;
  }
}

// W_c = W_ih @ W_lin  (384x128), fp32 accumulate -> bf16
__global__ __launch_bounds__(256) void wcomp_k(const float* __restrict__ Wih,
                                               const float* __restrict__ Wlin,
                                               unsigned short* __restrict__ Wcb) {
  int gid = blockIdx.x * 256 + threadIdx.x;   // 49152 = 384*128
  int i = gid >> 7, j = gid & 127;
  float acc = 0.f;
  #pragma unroll 8
  for (int k = 0; k < 128; ++k)
    acc += Wih[i * 128 + k] * Wlin[k * 128 + j];
  Wcb[i * 128 + j] = f2bf(acc);
}

__global__ void zero_k(int* __restrict__ p, int n) {
  int i = blockIdx.x * blockDim.x + threadIdx.x;
  if (i < n) p[i] = 0;
}

// ---------------- CSR build ----------------
__global__ void hist_k(const int* __restrict__ dst, int* __restrict__ cnt, int n) {
  int i = blockIdx.x * blockDim.x + threadIdx.x;
  if (i < n) atomicAdd(&cnt[dst[i]], 1);
}

__global__ __launch_bounds__(256) void scan1_k(const int* __restrict__ cnt,
                                               int* __restrict__ rowptr,
                                               int* __restrict__ bsum, int N) {
  __shared__ int wtot[4];
  int tid = threadIdx.x, lane = tid & 63, w = tid >> 6;
  int i = blockIdx.x * 256 + tid;
  int v = (i < N) ? cnt[i] : 0;
  int x = v;
  #pragma unroll
  for (int off = 1; off < 64; off <<= 1) {
    int t = __shfl_up(x, off, 64);
    if (lane >= off) x += t;
  }
  if (lane == 63) wtot[w] = x;
  __syncthreads();
  int woff = 0;
  for (int j = 0; j < w; ++j) woff += wtot[j];
  int excl = x - v + woff;
  if (i < N) rowptr[i] = excl;
  if (tid == 255) bsum[blockIdx.x] = excl + v;
}

__global__ __launch_bounds__(256) void scan2_k(int* __restrict__ bsum, int* __restrict__ rowptr, int NB) {
  __shared__ int wtot[4];
  int tid = threadIdx.x, lane = tid & 63, w = tid >> 6;
  int v = (tid < NB) ? bsum[tid] : 0;
  int x = v;
  #pragma unroll
  for (int off = 1; off < 64; off <<= 1) {
    int t = __shfl_up(x, off, 64);
    if (lane >= off) x += t;
  }
  if (lane == 63) wtot[w] = x;
  __syncthreads();
  int woff = 0;
  for (int j = 0; j < w; ++j) woff += wtot[j];
  int excl = x - v + woff;
  if (tid < NB) bsum[tid] = excl;
  if (tid == 255) rowptr[NN] = excl + v;
}

__global__ void scan3_k(int* __restrict__ rowptr, const int* __restrict__ bsum,
                        int* __restrict__ cursor, int N) {
  int i = blockIdx.x * 256 + threadIdx.x;
  if (i < N) {
    int r = rowptr[i] + bsum[i >> 8];
    rowptr[i] = r;
    cursor[i] = r;
  }
}

__global__ void fill_k(const int* __restrict__ src, const int* __restrict__ dst,
                       int* __restrict__ cursor, int* __restrict__ colx, int n) {
  int i = blockIdx.x * blockDim.x + threadIdx.x;
  if (i < n) {
    int pos = atomicAdd(&cursor[dst[i]], 1);
    colx[pos] = src[i];
  }
}

// ---------------- aggregated_state = segment_sum(state[src], dst) ----------------
__global__ __launch_bounds__(256) void agg_k(const unsigned short* __restrict__ M,
                                             const int* __restrict__ rowptr,
                                             const int* __restrict__ colx,
                                             unsigned short* __restrict__ P, int N) {
  int wid = (blockIdx.x * 256 + threadIdx.x) >> 6;
  int lane = threadIdx.x & 63;
  if (wid >= N) return;
  int beg = rowptr[wid], end = rowptr[wid + 1];
  float a0 = 0.f, a1 = 0.f, b0 = 0.f, b1 = 0.f;
  int e = beg;
  for (; e + 4 <= end; e += 4) {
    int s0 = colx[e], s1 = colx[e + 1], s2 = colx[e + 2], s3 = colx[e + 3];
    unsigned int v0 = *(const unsigned int*)(M + s0 * CC + lane * 2);
    unsigned int v1 = *(const unsigned int*)(M + s1 * CC + lane * 2);
    unsigned int v2 = *(const unsigned int*)(M + s2 * CC + lane * 2);
    unsigned int v3 = *(const unsigned int*)(M + s3 * CC + lane * 2);
    a0 += bf2f(v0 & 0xffffu); a1 += bf2f(v0 >> 16);
    b0 += bf2f(v1 & 0xffffu); b1 += bf2f(v1 >> 16);
    a0 += bf2f(v2 & 0xffffu); a1 += bf2f(v2 >> 16);
    b0 += bf2f(v3 & 0xffffu); b1 += bf2f(v3 >> 16);
  }
  for (; e < end; ++e) {
    int s = colx[e];
    unsigned int v = *(const unsigned int*)(M + s * CC + lane * 2);
    a0 += bf2f(v & 0xffffu); a1 += bf2f(v >> 16);
  }
  a0 += b0; a1 += b1;
  unsigned int o = (unsigned int)f2bf(a0) | ((unsigned int)f2bf(a1) << 16);
  *(unsigned int*)(P + wid * CC + lane * 2) = o;
}

// ---------------- fused gate GEMMs + GRU elementwise (weights-stationary) ----------------
__global__ __launch_bounds__(256) void gru2_k(const unsigned short* __restrict__ Pb,
                                              const unsigned short* __restrict__ Sb_in,
                                              unsigned short* __restrict__ Sb_out,
                                              const float* __restrict__ h_in,
                                              float* __restrict__ h_out,
                                              const unsigned short* __restrict__ Wcb,
                                              const unsigned short* __restrict__ Whhb,
                                              const float* __restrict__ bih,
                                              const float* __restrict__ bhh) {
  __shared__ unsigned short sW[6][64][128];      // 96 KB
  __shared__ unsigned short sA[2][2][32][128];   // 32 KB
  const int tid = threadIdx.x;
  const int half = blockIdx.x & 1;
  const int group = blockIdx.x >> 1;
  const int lane = tid & 63, w = tid >> 6;
  const int l15 = lane & 15, l4 = lane >> 4;

  for (int idx = tid; idx < 6144; idx += 256) {
    int pi = idx >> 10, j = idx & 1023, c = j >> 4, ch = j & 15;
    const unsigned short* Wm = (pi < 3) ? Wcb : Whhb;
    int p = (pi < 3) ? pi : pi - 3;
    int gcol = p * 128 + half * 64 + c;
    uint4 v = *(const uint4*)(Wm + gcol * 128 + ch * 8);
    *(uint4*)&sW[pi][c][((ch ^ (c & 15)) * 8)] = v;
  }

  const int c_loc = w * 16 + l15;
  const int cg = half * 64 + c_loc;
  const float bir = bih[cg], biz = bih[cg + 128], bin_ = bih[cg + 256];
  const float bhr = bhh[cg], bhz = bhh[cg + 128], bhn = bhh[cg + 256];

  auto loadA = [&](int t, uint4* r) {
    int rowbase = t * 32;
    #pragma unroll
    for (int k = 0; k < 4; ++k) {
      int idx = k * 256 + tid;
      int mat = idx >> 9, j = idx & 511, row = j >> 4, ch = j & 15;
      int grow = rowbase + row;
      const unsigned short* srcp = mat ? Sb_in : Pb;
      r[k] = (grow < NN) ? *(const uint4*)(srcp + grow * 128 + ch * 8) : make_uint4(0, 0, 0, 0);
    }
  };
  auto writeA = [&](int buf, const uint4* r) {
    #pragma unroll
    for (int k = 0; k < 4; ++k) {
      int idx = k * 256 + tid;
      int mat = idx >> 9, j = idx & 511, row = j >> 4, ch = j & 15;
      *(uint4*)&sA[buf][mat][row][((ch ^ (row & 15)) * 8)] = r[k];
    }
  };

  uint4 pre[4];
  int t0 = group;
  loadA(t0, pre);
  writeA(0, pre);
  int cur = 0;
  for (int t = t0; t < NT; t += 256) {
    __syncthreads();
    int tn = t + 256;
    uint4 nxt[4];
    if (tn < NT) loadA(tn, nxt);

    f32x4 acc[6][2] = {};
    #pragma unroll
    for (int ks = 0; ks < 4; ++ks) {
      bf16x8 a[2][2];
      #pragma unroll
      for (int mat = 0; mat < 2; ++mat)
        #pragma unroll
        for (int rt = 0; rt < 2; ++rt) {
          int row = rt * 16 + l15;
          a[mat][rt] = *(const bf16x8*)&sA[cur][mat][row][(((ks * 4 + l4) ^ l15) * 8)];
        }
      #pragma unroll
      for (int pi = 0; pi < 6; ++pi) {
        bf16x8 b = *(const bf16x8*)&sW[pi][c_loc][(((ks * 4 + l4) ^ l15) * 8)];
        int am = (pi < 3) ? 0 : 1;
        acc[pi][0] = __builtin_amdgcn_mfma_f32_16x16x32_bf16(a[am][0], b, acc[pi][0], 0, 0, 0);
        acc[pi][1] = __builtin_amdgcn_mfma_f32_16x16x32_bf16(a[am][1], b, acc[pi][1], 0, 0, 0);
      }
    }

    int rowbase = t * 32;
    #pragma unroll
    for (int rt = 0; rt < 2; ++rt)
      #pragma unroll
      for (int i = 0; i < 4; ++i) {
        int row = rowbase + rt * 16 + l4 * 4 + i;
        if (row < NN) {
          float gir = acc[0][rt][i] + bir;
          float giz = acc[1][rt][i] + biz;
          float gin = acc[2][rt][i] + bin_;
          float ghr = acc[3][rt][i] + bhr;
          float ghz = acc[4][rt][i] + bhz;
          float ghn = acc[5][rt][i] + bhn;
          float r = 1.f / (1.f + __expf(-(gir + ghr)));
          float z = 1.f / (1.f + __expf(-(giz + ghz)));
          float n = tanhf(gin + r * ghn);
          float h = h_in[row * 128 + cg];
          float o = (1.f - z) * n + z * h;
          h_out[row * 128 + cg] = o;
          Sb_out[row * 128 + cg] = f2bf(o);
        }
      }
    if (tn < NT) writeA(cur ^ 1, nxt);
    cur ^= 1;
  }
}

extern "C" void kernel_launch(void* const* d_in, const int* in_sizes, int n_in,
                              void* d_out, int out_size, void* d_ws, size_t ws_size,
                              hipStream_t stream) {
  const float* x    = (const float*)d_in[0];
  const int*   ei   = (const int*)d_in[1];
  const float* Wlin = (const float*)d_in[2];
  const float* Wih  = (const float*)d_in[3];
  const float* Whh  = (const float*)d_in[4];
  const float* bih  = (const float*)d_in[5];
  const float* bhh  = (const float*)d_in[6];
  float* out = (float*)d_out;

  char* ws = (char*)d_ws;
  size_t off = 0;
  auto alloc = [&](size_t bytes) -> void* {
    void* p = ws + off;
    off += (bytes + 255) & ~(size_t)255;
    return p;
  };
  unsigned short* SbA  = (unsigned short*)alloc((size_t)NN * CC * 2);
  unsigned short* SbB  = (unsigned short*)alloc((size_t)NN * CC * 2);
  unsigned short* Prb  = (unsigned short*)alloc((size_t)NN * CC * 2);
  float*          Sf   = (float*)alloc((size_t)NN * CC * 4);
  unsigned short* Wcb  = (unsigned short*)alloc((size_t)3 * CC * CC * 2);
  unsigned short* Whhb = (unsigned short*)alloc((size_t)3 * CC * CC * 2);
  int* rowptr = (int*)alloc((size_t)(NN + 1) * 4);
  int* cursor = (int*)alloc((size_t)NN * 4);
  int* colx   = (int*)alloc((size_t)EE * 4);
  int* bsum   = (int*)alloc(256 * 4);

  const int* srcI = ei;
  const int* dstI = ei + EE;

  cast_f2b_k<<<1024, 256, 0, stream>>>(x, SbA, NN * CC / 4);
  cast_f2b_k<<<48, 256, 0, stream>>>(Whh, Whhb, 3 * CC * CC / 4);
  wcomp_k<<<192, 256, 0, stream>>>(Wih, Wlin, Wcb);

  zero_k<<<NBLK, 256, 0, stream>>>(cursor, NN);
  hist_k<<<(EE + 255) / 256, 256, 0, stream>>>(dstI, cursor, EE);
  scan1_k<<<NBLK, 256, 0, stream>>>(cursor, rowptr, bsum, NN);
  scan2_k<<<1, 256, 0, stream>>>(bsum, rowptr, NBLK);
  scan3_k<<<NBLK, 256, 0, stream>>>(rowptr, bsum, cursor, NN);
  fill_k<<<(EE + 255) / 256, 256, 0, stream>>>(srcI, dstI, cursor, colx, EE);

  const int aggBlocks = (NN + 3) / 4;

  // step 1 (h = x, state = bf16(x))
  agg_k<<<aggBlocks, 256, 0, stream>>>(SbA, rowptr, colx, Prb, NN);
  gru2_k<<<512, 256, 0, stream>>>(Prb, SbA, SbB, x, Sf, Wcb, Whhb, bih, bhh);
  // step 2
  agg_k<<<aggBlocks, 256, 0, stream>>>(SbB, rowptr, colx, Prb, NN);
  gru2_k<<<512, 256, 0, stream>>>(Prb, SbB, SbA, Sf, Sf, Wcb, Whhb, bih, bhh);
  // step 3 (final state -> d_out)
  agg_k<<<aggBlocks, 256, 0, stream>>>(SbA, rowptr, colx, Prb, NN);
  gru2_k<<<512, 256, 0, stream>>>(Prb, SbA, SbB, Sf, out, Wcb, Whhb, bih, bhh);
}

// Round 6
// 395.670 us; speedup vs baseline: 1.8322x; 1.2933x over previous
//
#include <hip/hip_runtime.h>

#define NN 50000
#define CC 128
#define EE 800000
#define NT 1563          // ceil(NN/32)
#define NBLK 196         // ceil(NN/256)

typedef short bf16x8 __attribute__((ext_vector_type(8)));
typedef float f32x4 __attribute__((ext_vector_type(4)));

__device__ __forceinline__ float bf2f(unsigned int u16) {
  union { unsigned int u; float f; } x; x.u = u16 << 16; return x.f;
}
__device__ __forceinline__ unsigned short f2bf(float f) {
  union { float f; unsigned int u; } x; x.f = f;
  unsigned int u = x.u;
  unsigned int r = (u + 0x7fffu + ((u >> 16) & 1u)) >> 16;
  return (unsigned short)r;
}

// ---------------- casts ----------------
__global__ void cast_f2b_k(const float* __restrict__ in, unsigned short* __restrict__ out, int n4) {
  int i = blockIdx.x * blockDim.x + threadIdx.x;
  int stride = gridDim.x * blockDim.x;
  for (; i < n4; i += stride) {
    float4 v = ((const float4*)in)[i];
    ushort4 o;
    o.x = f2bf(v.x); o.y = f2bf(v.y); o.z = f2bf(v.z); o.w = f2bf(v.w);
    ((ushort4*)out)[i] = o;
  }
}

// W_c = W_ih @ W_lin  (384x128), fp32 accumulate -> bf16
__global__ __launch_bounds__(256) void wcomp_k(const float* __restrict__ Wih,
                                               const float* __restrict__ Wlin,
                                               unsigned short* __restrict__ Wcb) {
  int gid = blockIdx.x * 256 + threadIdx.x;   // 49152 = 384*128
  int i = gid >> 7, j = gid & 127;
  float acc = 0.f;
  #pragma unroll 8
  for (int k = 0; k < 128; ++k)
    acc += Wih[i * 128 + k] * Wlin[k * 128 + j];
  Wcb[i * 128 + j] = f2bf(acc);
}

__global__ void zero_k(int* __restrict__ p, int n) {
  int i = blockIdx.x * blockDim.x + threadIdx.x;
  if (i < n) p[i] = 0;
}

// ---------------- CSR build ----------------
__global__ void hist_k(const int* __restrict__ dst, int* __restrict__ cnt, int n) {
  int i = blockIdx.x * blockDim.x + threadIdx.x;
  if (i < n) atomicAdd(&cnt[dst[i]], 1);
}

__global__ __launch_bounds__(256) void scan1_k(const int* __restrict__ cnt,
                                               int* __restrict__ rowptr,
                                               int* __restrict__ bsum, int N) {
  __shared__ int wtot[4];
  int tid = threadIdx.x, lane = tid & 63, w = tid >> 6;
  int i = blockIdx.x * 256 + tid;
  int v = (i < N) ? cnt[i] : 0;
  int x = v;
  #pragma unroll
  for (int off = 1; off < 64; off <<= 1) {
    int t = __shfl_up(x, off, 64);
    if (lane >= off) x += t;
  }
  if (lane == 63) wtot[w] = x;
  __syncthreads();
  int woff = 0;
  for (int j = 0; j < w; ++j) woff += wtot[j];
  int excl = x - v + woff;
  if (i < N) rowptr[i] = excl;
  if (tid == 255) bsum[blockIdx.x] = excl + v;
}

__global__ __launch_bounds__(256) void scan2_k(int* __restrict__ bsum, int* __restrict__ rowptr, int NB) {
  __shared__ int wtot[4];
  int tid = threadIdx.x, lane = tid & 63, w = tid >> 6;
  int v = (tid < NB) ? bsum[tid] : 0;
  int x = v;
  #pragma unroll
  for (int off = 1; off < 64; off <<= 1) {
    int t = __shfl_up(x, off, 64);
    if (lane >= off) x += t;
  }
  if (lane == 63) wtot[w] = x;
  __syncthreads();
  int woff = 0;
  for (int j = 0; j < w; ++j) woff += wtot[j];
  int excl = x - v + woff;
  if (tid < NB) bsum[tid] = excl;
  if (tid == 255) rowptr[NN] = excl + v;
}

__global__ void scan3_k(int* __restrict__ rowptr, const int* __restrict__ bsum,
                        int* __restrict__ cursor, int N) {
  int i = blockIdx.x * 256 + threadIdx.x;
  if (i < N) {
    int r = rowptr[i] + bsum[i >> 8];
    rowptr[i] = r;
    cursor[i] = r;
  }
}

__global__ void fill_k(const int* __restrict__ src, const int* __restrict__ dst,
                       int* __restrict__ cursor, int* __restrict__ colx, int n) {
  int i = blockIdx.x * blockDim.x + threadIdx.x;
  if (i < n) {
    int pos = atomicAdd(&cursor[dst[i]], 1);
    colx[pos] = src[i];
  }
}

// ---------------- aggregated_state = segment_sum(state[src], dst) ----------------
// wave per dst row; lanes 0-31 / 32-63 process interleaved edges (8 rows in flight)
__global__ __launch_bounds__(256) void agg2_k(const unsigned short* __restrict__ M,
                                              const int* __restrict__ rowptr,
                                              const int* __restrict__ colx,
                                              unsigned short* __restrict__ P, int N) {
  int wid = (blockIdx.x * 256 + threadIdx.x) >> 6;
  int lane = threadIdx.x & 63;
  if (wid >= N) return;
  int beg = rowptr[wid], end = rowptr[wid + 1];
  int half = lane >> 5, li = lane & 31;
  float a0 = 0.f, a1 = 0.f, a2 = 0.f, a3 = 0.f;
  int n = end - beg;
  int i = 0;
  for (; i + 8 <= n; i += 8) {
    int e = beg + i + half;
    int s0 = colx[e], s1 = colx[e + 2], s2 = colx[e + 4], s3 = colx[e + 6];
    uint2 v0 = *(const uint2*)(M + s0 * CC + li * 4);
    uint2 v1 = *(const uint2*)(M + s1 * CC + li * 4);
    uint2 v2 = *(const uint2*)(M + s2 * CC + li * 4);
    uint2 v3 = *(const uint2*)(M + s3 * CC + li * 4);
    a0 += bf2f(v0.x & 0xffffu); a1 += bf2f(v0.x >> 16); a2 += bf2f(v0.y & 0xffffu); a3 += bf2f(v0.y >> 16);
    a0 += bf2f(v1.x & 0xffffu); a1 += bf2f(v1.x >> 16); a2 += bf2f(v1.y & 0xffffu); a3 += bf2f(v1.y >> 16);
    a0 += bf2f(v2.x & 0xffffu); a1 += bf2f(v2.x >> 16); a2 += bf2f(v2.y & 0xffffu); a3 += bf2f(v2.y >> 16);
    a0 += bf2f(v3.x & 0xffffu); a1 += bf2f(v3.x >> 16); a2 += bf2f(v3.y & 0xffffu); a3 += bf2f(v3.y >> 16);
  }
  for (; i + 2 <= n; i += 2) {
    int e = beg + i + half;
    int s = colx[e];
    uint2 v = *(const uint2*)(M + s * CC + li * 4);
    a0 += bf2f(v.x & 0xffffu); a1 += bf2f(v.x >> 16); a2 += bf2f(v.y & 0xffffu); a3 += bf2f(v.y >> 16);
  }
  if (i < n && half == 0) {
    int s = colx[beg + i];
    uint2 v = *(const uint2*)(M + s * CC + li * 4);
    a0 += bf2f(v.x & 0xffffu); a1 += bf2f(v.x >> 16); a2 += bf2f(v.y & 0xffffu); a3 += bf2f(v.y >> 16);
  }
  a0 += __shfl_xor(a0, 32, 64);
  a1 += __shfl_xor(a1, 32, 64);
  a2 += __shfl_xor(a2, 32, 64);
  a3 += __shfl_xor(a3, 32, 64);
  if (half == 0) {
    uint2 o;
    o.x = (unsigned int)f2bf(a0) | ((unsigned int)f2bf(a1) << 16);
    o.y = (unsigned int)f2bf(a2) | ((unsigned int)f2bf(a3) << 16);
    *(uint2*)(P + wid * CC + li * 4) = o;
  }
}

// ---------------- fused gate GEMMs + GRU elementwise (weights in VGPRs) ----------------
// grid = 512: blockIdx&1 = column half (64 gate-cols), blockIdx>>1 = row group (stride 256)
__global__ __launch_bounds__(256, 2) void gru3_k(const unsigned short* __restrict__ Pb,
                                                 const unsigned short* __restrict__ Sb_in,
                                                 unsigned short* __restrict__ Sb_out,
                                                 const float* __restrict__ h_in,
                                                 float* __restrict__ h_out,
                                                 const unsigned short* __restrict__ Wcb,
                                                 const unsigned short* __restrict__ Whhb,
                                                 const float* __restrict__ bih,
                                                 const float* __restrict__ bhh) {
  __shared__ unsigned short sA[2][2][32][128];   // 32 KB: [buf][mat 0=agg 1=state]
  const int tid = threadIdx.x;
  const int half = blockIdx.x & 1;
  const int group = blockIdx.x >> 1;
  const int lane = tid & 63, w = tid >> 6;
  const int l15 = lane & 15, l4 = lane >> 4;

  const int c_loc = w * 16 + l15;
  const int cg = half * 64 + c_loc;

  // B fragments in registers: 6 panels x 4 k-steps x bf16x8 = 96 VGPR/lane.
  // Same addresses for all row-group blocks -> L2-resident after first touch.
  bf16x8 Breg[6][4];
  #pragma unroll
  for (int pi = 0; pi < 6; ++pi) {
    const unsigned short* Wm = (pi < 3) ? Wcb : Whhb;
    int p = (pi < 3) ? pi : pi - 3;
    const unsigned short* base = Wm + (p * 128 + cg) * 128 + l4 * 8;
    #pragma unroll
    for (int ks = 0; ks < 4; ++ks)
      Breg[pi][ks] = *(const bf16x8*)(base + ks * 32);
  }

  const float bir = bih[cg], biz = bih[cg + 128], bin_ = bih[cg + 256];
  const float bhr = bhh[cg], bhz = bhh[cg + 128], bhn = bhh[cg + 256];

  auto loadA = [&](int t, uint4* r) {
    int rowbase = t * 32;
    #pragma unroll
    for (int k = 0; k < 4; ++k) {
      int idx = k * 256 + tid;                 // 1024 chunks: [mat][row][ch]
      int mat = idx >> 9, j = idx & 511, row = j >> 4, ch = j & 15;
      int grow = rowbase + row;
      const unsigned short* srcp = mat ? Sb_in : Pb;
      r[k] = (grow < NN) ? *(const uint4*)(srcp + grow * 128 + ch * 8) : make_uint4(0, 0, 0, 0);
    }
  };
  auto writeA = [&](int buf, const uint4* r) {
    #pragma unroll
    for (int k = 0; k < 4; ++k) {
      int idx = k * 256 + tid;
      int mat = idx >> 9, j = idx & 511, row = j >> 4, ch = j & 15;
      *(uint4*)&sA[buf][mat][row][((ch ^ (row & 15)) * 8)] = r[k];
    }
  };

  uint4 pre[4];
  int t0 = group;
  loadA(t0, pre);
  writeA(0, pre);
  int cur = 0;
  for (int t = t0; t < NT; t += 256) {
    __syncthreads();
    int tn = t + 256;
    uint4 nxt[4];
    if (tn < NT) loadA(tn, nxt);

    f32x4 acc[6][2] = {};
    #pragma unroll
    for (int ks = 0; ks < 4; ++ks) {
      bf16x8 a[2][2];
      #pragma unroll
      for (int mat = 0; mat < 2; ++mat)
        #pragma unroll
        for (int rt = 0; rt < 2; ++rt) {
          int row = rt * 16 + l15;
          a[mat][rt] = *(const bf16x8*)&sA[cur][mat][row][(((ks * 4 + l4) ^ l15) * 8)];
        }
      #pragma unroll
      for (int pi = 0; pi < 6; ++pi) {
        int am = (pi < 3) ? 0 : 1;
        acc[pi][0] = __builtin_amdgcn_mfma_f32_16x16x32_bf16(a[am][0], Breg[pi][ks], acc[pi][0], 0, 0, 0);
        acc[pi][1] = __builtin_amdgcn_mfma_f32_16x16x32_bf16(a[am][1], Breg[pi][ks], acc[pi][1], 0, 0, 0);
      }
    }

    int rowbase = t * 32;
    #pragma unroll
    for (int rt = 0; rt < 2; ++rt)
      #pragma unroll
      for (int i = 0; i < 4; ++i) {
        int row = rowbase + rt * 16 + l4 * 4 + i;
        if (row < NN) {
          float gir = acc[0][rt][i] + bir;
          float giz = acc[1][rt][i] + biz;
          float gin = acc[2][rt][i] + bin_;
          float ghr = acc[3][rt][i] + bhr;
          float ghz = acc[4][rt][i] + bhz;
          float ghn = acc[5][rt][i] + bhn;
          float r = 1.f / (1.f + __expf(-(gir + ghr)));
          float z = 1.f / (1.f + __expf(-(giz + ghz)));
          float n = tanhf(gin + r * ghn);
          float h = h_in[row * 128 + cg];
          float o = (1.f - z) * n + z * h;
          h_out[row * 128 + cg] = o;
          Sb_out[row * 128 + cg] = f2bf(o);
        }
      }
    if (tn < NT) writeA(cur ^ 1, nxt);
    cur ^= 1;
  }
}

extern "C" void kernel_launch(void* const* d_in, const int* in_sizes, int n_in,
                              void* d_out, int out_size, void* d_ws, size_t ws_size,
                              hipStream_t stream) {
  const float* x    = (const float*)d_in[0];
  const int*   ei   = (const int*)d_in[1];
  const float* Wlin = (const float*)d_in[2];
  const float* Wih  = (const float*)d_in[3];
  const float* Whh  = (const float*)d_in[4];
  const float* bih  = (const float*)d_in[5];
  const float* bhh  = (const float*)d_in[6];
  float* out = (float*)d_out;

  char* ws = (char*)d_ws;
  size_t off = 0;
  auto alloc = [&](size_t bytes) -> void* {
    void* p = ws + off;
    off += (bytes + 255) & ~(size_t)255;
    return p;
  };
  unsigned short* SbA  = (unsigned short*)alloc((size_t)NN * CC * 2);
  unsigned short* SbB  = (unsigned short*)alloc((size_t)NN * CC * 2);
  unsigned short* Prb  = (unsigned short*)alloc((size_t)NN * CC * 2);
  float*          Sf   = (float*)alloc((size_t)NN * CC * 4);
  unsigned short* Wcb  = (unsigned short*)alloc((size_t)3 * CC * CC * 2);
  unsigned short* Whhb = (unsigned short*)alloc((size_t)3 * CC * CC * 2);
  int* rowptr = (int*)alloc((size_t)(NN + 1) * 4);
  int* cursor = (int*)alloc((size_t)NN * 4);
  int* colx   = (int*)alloc((size_t)EE * 4);
  int* bsum   = (int*)alloc(256 * 4);

  const int* srcI = ei;
  const int* dstI = ei + EE;

  cast_f2b_k<<<1024, 256, 0, stream>>>(x, SbA, NN * CC / 4);
  cast_f2b_k<<<48, 256, 0, stream>>>(Whh, Whhb, 3 * CC * CC / 4);
  wcomp_k<<<192, 256, 0, stream>>>(Wih, Wlin, Wcb);

  zero_k<<<NBLK, 256, 0, stream>>>(cursor, NN);
  hist_k<<<(EE + 255) / 256, 256, 0, stream>>>(dstI, cursor, EE);
  scan1_k<<<NBLK, 256, 0, stream>>>(cursor, rowptr, bsum, NN);
  scan2_k<<<1, 256, 0, stream>>>(bsum, rowptr, NBLK);
  scan3_k<<<NBLK, 256, 0, stream>>>(rowptr, bsum, cursor, NN);
  fill_k<<<(EE + 255) / 256, 256, 0, stream>>>(srcI, dstI, cursor, colx, EE);

  const int aggBlocks = (NN + 3) / 4;

  // step 1 (h = x, state = bf16(x))
  agg2_k<<<aggBlocks, 256, 0, stream>>>(SbA, rowptr, colx, Prb, NN);
  gru3_k<<<512, 256, 0, stream>>>(Prb, SbA, SbB, x, Sf, Wcb, Whhb, bih, bhh);
  // step 2
  agg2_k<<<aggBlocks, 256, 0, stream>>>(SbB, rowptr, colx, Prb, NN);
  gru3_k<<<512, 256, 0, stream>>>(Prb, SbB, SbA, Sf, Sf, Wcb, Whhb, bih, bhh);
  // step 3 (final state -> d_out)
  agg2_k<<<aggBlocks, 256, 0, stream>>>(SbA, rowptr, colx, Prb, NN);
  gru3_k<<<512, 256, 0, stream>>>(Prb, SbA, SbB, Sf, out, Wcb, Whhb, bih, bhh);
}